// Round 14
// baseline (677.173 us; speedup 1.0000x reference)
//
#include <hip/hip_runtime.h>
#include <hip/hip_bf16.h>
#include <stdint.h>

#define T_TOK 4096
#define NEXP  8
#define HDIM  1024
#define IDIM  2048
#define TOPK  2

typedef __attribute__((ext_vector_type(8))) short short8;
typedef __attribute__((ext_vector_type(4))) float f32x4;

__device__ __forceinline__ unsigned short f2bf(float f) {
    union { float f; unsigned int u; } v; v.f = f;
    unsigned int u = v.u;
    return (unsigned short)((u + 0x7fffu + ((u >> 16) & 1u)) >> 16);
}
__device__ __forceinline__ void gload_lds16(const void* g, void* l) {
    __builtin_amdgcn_global_load_lds(
        (const __attribute__((address_space(1))) unsigned int*)g,
        (__attribute__((address_space(3))) unsigned int*)l,
        16, 0, 0);
}
#define MFMA16(A, B, C) __builtin_amdgcn_mfma_f32_16x16x32_bf16(A, B, C, 0, 0, 0)

// ---------------- prep: routing (block 0) ∥ x+w13 fp32->bf16 (blocks 1+) ----------------

__global__ __launch_bounds__(1024) void prep_k(
    const float* __restrict__ logits, const float* __restrict__ x,
    const float* __restrict__ w13, int* __restrict__ offs, int* __restrict__ work,
    int* __restrict__ tokid, float* __restrict__ tokw,
    unsigned short* __restrict__ xb, unsigned short* __restrict__ w13b)
{
    const int tid = threadIdx.x;
    if (blockIdx.x == 0) {
        __shared__ int cnt[NEXP];
        __shared__ int cur[NEXP];
        if (tid < NEXP) cnt[tid] = 0;
        __syncthreads();
        int e0v[4], e1v[4];
        float w0v[4], w1v[4];
        #pragma unroll
        for (int it = 0; it < 4; ++it) {
            int t = tid + it * 1024;
            const float4* lp = (const float4*)(logits + (size_t)t * NEXP);
            float4 a = lp[0], b = lp[1];
            float l[NEXP] = {a.x, a.y, a.z, a.w, b.x, b.y, b.z, b.w};
            int e0 = 0; float b0 = l[0];
            #pragma unroll
            for (int e = 1; e < NEXP; ++e) if (l[e] > b0) { b0 = l[e]; e0 = e; }
            int e1 = -1; float b1 = -1e30f;
            #pragma unroll
            for (int e = 0; e < NEXP; ++e) { if (e == e0) continue; if (l[e] > b1) { b1 = l[e]; e1 = e; } }
            float tt = __expf(b1 - b0);
            float w0 = 1.0f / (1.0f + tt);
            e0v[it] = e0; e1v[it] = e1; w0v[it] = w0; w1v[it] = 1.0f - w0;
            atomicAdd(&cnt[e0], 1);
            atomicAdd(&cnt[e1], 1);
        }
        __syncthreads();
        if (tid == 0) {
            int s = 0, n = 0;
            for (int e = 0; e < NEXP; ++e) {
                offs[e] = s; cur[e] = s;
                int nm = (cnt[e] + 127) >> 7;
                for (int m = 0; m < nm; ++m) work[1 + n++] = (e << 8) | m;
                s += cnt[e];
            }
            offs[NEXP] = s;
            work[0] = n;
        }
        __syncthreads();
        #pragma unroll
        for (int it = 0; it < 4; ++it) {
            int t = tid + it * 1024;
            int p0 = atomicAdd(&cur[e0v[it]], 1);
            tokid[p0] = t; tokw[p0] = w0v[it];
            int p1 = atomicAdd(&cur[e1v[it]], 1);
            tokid[p1] = t; tokw[p1] = w1v[it];
        }
        return;
    }
    const int n0 = T_TOK * HDIM / 8;
    const int n1 = NEXP * 2 * IDIM * HDIM / 8;
    const int total = n0 + n1;
    for (int i = (blockIdx.x - 1) * 1024 + tid; i < total; i += (int)(gridDim.x - 1) * 1024) {
        const float* s; unsigned short* d; int j;
        if (i < n0) { s = x; d = xb; j = i; }
        else { s = w13; d = w13b; j = i - n0; }
        const float4* p4 = (const float4*)(s + (size_t)j * 8);
        float4 a = p4[0], b = p4[1];
        union { unsigned short us[8]; short8 v; } r;
        r.us[0] = f2bf(a.x); r.us[1] = f2bf(a.y); r.us[2] = f2bf(a.z); r.us[3] = f2bf(a.w);
        r.us[4] = f2bf(b.x); r.us[5] = f2bf(b.y); r.us[6] = f2bf(b.z); r.us[7] = f2bf(b.w);
        *(short8*)(d + (size_t)j * 8) = r.v;
    }
}

// ---------------- g1c2: gemm1 (blocks [0,1152)) ∥ w2 conversion (blocks [1152,1408)) ----------
// gemm1 first in dispatch order so both rounds of GEMM blocks start ASAP;
// w2-cvt fills the retirement raggedness at the tail.

#define G1B  1152   // 16 nt x 72 work slots
#define CVTB 256

__global__ __launch_bounds__(256, 3) void g1c2_k(
    const unsigned short* __restrict__ xb, const unsigned short* __restrict__ w13b,
    const float* __restrict__ w2, unsigned short* __restrict__ w2b,
    const int* __restrict__ tokid, const int* __restrict__ offs,
    const int* __restrict__ work, unsigned short* __restrict__ hbuf)
{
    __shared__ __align__(16) unsigned short As[128 * 64];
    __shared__ __align__(16) unsigned short Bg[128 * 64];
    __shared__ __align__(16) unsigned short Bu[128 * 64];

    const int bid = blockIdx.x;
    if (bid >= G1B) {
        // ---- w2 conversion (tail blocks)
        const int cb = bid - G1B;
        const int n2 = NEXP * HDIM * IDIM / 8;
        for (int i = cb * 256 + threadIdx.x; i < n2; i += CVTB * 256) {
            const float4* p4 = (const float4*)(w2 + (size_t)i * 8);
            float4 a = p4[0], b = p4[1];
            union { unsigned short us[8]; short8 v; } r;
            r.us[0] = f2bf(a.x); r.us[1] = f2bf(a.y); r.us[2] = f2bf(a.z); r.us[3] = f2bf(a.w);
            r.us[4] = f2bf(b.x); r.us[5] = f2bf(b.y); r.us[6] = f2bf(b.z); r.us[7] = f2bf(b.w);
            *(short8*)(w2b + (size_t)i * 8) = r.v;
        }
        return;
    }

    const int id = bid;                              // 0..1151
    const int id2 = (id & 7) * 144 + (id >> 3);      // XCD-chunked bijective swizzle
    const int nt = id2 / 72;
    const int wki = id2 % 72;
    if (wki >= work[0]) return;
    const int wk = work[1 + wki];
    const int e = wk >> 8, mt = wk & 255;
    const int off_e = offs[e];
    const int cnt_e = offs[e + 1] - off_e;

    const int tid = threadIdx.x;
    const int w = tid >> 6, lane = tid & 63;
    const int ln15 = lane & 15, l16 = lane >> 4;
    const int wm = w >> 1, wn = w & 1;

    const unsigned short* aSrc[4]; const unsigned short* gSrc[4]; const unsigned short* uSrc[4];
    int ldsOff[4];
    #pragma unroll
    for (int i = 0; i < 4; ++i) {
        int S = (i * 4 + w) * 64 + lane;
        int row = S >> 3;
        int ko = (S & 7) ^ (row & 7);
        ldsOff[i] = (i * 4 + w) * 512;
        int tr = mt * 128 + row; if (tr >= cnt_e) tr = cnt_e - 1;
        aSrc[i] = xb + (size_t)tokid[off_e + tr] * HDIM + ko * 8;
        gSrc[i] = w13b + (size_t)e * (2 * IDIM * HDIM) + (size_t)(nt * 128 + row) * HDIM + ko * 8;
        uSrc[i] = w13b + (size_t)e * (2 * IDIM * HDIM) + (size_t)(IDIM + nt * 128 + row) * HDIM + ko * 8;
    }

    const f32x4 z4 = {0.f, 0.f, 0.f, 0.f};
    f32x4 g[4][4], u[4][4];
    #pragma unroll
    for (int m = 0; m < 4; ++m)
        #pragma unroll
        for (int n = 0; n < 4; ++n) { g[m][n] = z4; u[m][n] = z4; }

    const int KT = HDIM / 64;   // 16
    for (int kt = 0; kt < KT; ++kt) {
        #pragma unroll
        for (int i = 0; i < 4; ++i) {
            gload_lds16(aSrc[i] + kt * 64, &As[ldsOff[i]]);
            gload_lds16(gSrc[i] + kt * 64, &Bg[ldsOff[i]]);
            gload_lds16(uSrc[i] + kt * 64, &Bu[ldsOff[i]]);
        }
        __syncthreads();
        #pragma unroll
        for (int kk = 0; kk < 2; ++kk) {
            short8 av[4], bgv[4], buv[4];
            int ko = kk * 4 + l16;
            #pragma unroll
            for (int m = 0; m < 4; ++m) {
                int row = wm * 64 + m * 16 + ln15;
                av[m] = *(const short8*)(As + row * 64 + ((ko ^ (row & 7)) * 8));
            }
            #pragma unroll
            for (int n = 0; n < 4; ++n) {
                int row = wn * 64 + n * 16 + ln15;
                int idx = row * 64 + ((ko ^ (row & 7)) * 8);
                bgv[n] = *(const short8*)(Bg + idx);
                buv[n] = *(const short8*)(Bu + idx);
            }
            __builtin_amdgcn_s_setprio(1);
            #pragma unroll
            for (int m = 0; m < 4; ++m)
                #pragma unroll
                for (int n = 0; n < 4; ++n) {
                    g[m][n] = MFMA16(av[m], bgv[n], g[m][n]);
                    u[m][n] = MFMA16(av[m], buv[n], u[m][n]);
                }
            __builtin_amdgcn_s_setprio(0);
        }
        __syncthreads();
    }

    // epilogue: h = silu(gate) * up -> bf16
    #pragma unroll
    for (int m = 0; m < 4; ++m) {
        #pragma unroll
        for (int i = 0; i < 4; ++i) {
            int r = mt * 128 + wm * 64 + m * 16 + l16 * 4 + i;
            if (r >= cnt_e) continue;
            size_t rb = (size_t)(off_e + r) * IDIM;
            #pragma unroll
            for (int n = 0; n < 4; ++n) {
                int col = nt * 128 + wn * 64 + n * 16 + ln15;
                float gv = g[m][n][i], uv = u[m][n][i];
                float hv = gv / (1.f + __expf(-gv)) * uv;
                hbuf[rb + col] = f2bf(hv);
            }
        }
    }
}

// ---------------- gemm2c: (h @ W2^T) * tokw + fused combine via f32 atomicAdd ----------------

__global__ __launch_bounds__(256, 3) void gemm2c_k(
    const unsigned short* __restrict__ hbuf, const unsigned short* __restrict__ w2b,
    const int* __restrict__ tokid, const int* __restrict__ offs,
    const int* __restrict__ work, const float* __restrict__ tokw,
    float* __restrict__ out)
{
    __shared__ __align__(16) unsigned short As[128 * 64];
    __shared__ __align__(16) unsigned short Bs[128 * 64];

    const int id = blockIdx.y * gridDim.x + blockIdx.x;   // 0..575
    const int id2 = (id & 7) * 72 + (id >> 3);
    const int nt = id2 / 72;
    const int wki = id2 % 72;
    if (wki >= work[0]) return;
    const int wk = work[1 + wki];
    const int e = wk >> 8, mt = wk & 255;
    const int off_e = offs[e];
    const int cnt_e = offs[e + 1] - off_e;

    const int tid = threadIdx.x;
    const int w = tid >> 6, lane = tid & 63;
    const int ln15 = lane & 15, l16 = lane >> 4;
    const int wm = w >> 1, wn = w & 1;

    const unsigned short* aSrc[4]; const unsigned short* bSrc[4];
    int ldsOff[4];
    #pragma unroll
    for (int i = 0; i < 4; ++i) {
        int S = (i * 4 + w) * 64 + lane;
        int row = S >> 3;
        int ko = (S & 7) ^ (row & 7);
        ldsOff[i] = (i * 4 + w) * 512;
        int tr = mt * 128 + row; if (tr >= cnt_e) tr = cnt_e - 1;
        aSrc[i] = hbuf + (size_t)(off_e + tr) * IDIM + ko * 8;
        bSrc[i] = w2b + (size_t)e * (HDIM * IDIM) + (size_t)(nt * 128 + row) * IDIM + ko * 8;
    }

    const f32x4 z4 = {0.f, 0.f, 0.f, 0.f};
    f32x4 acc[4][4];
    #pragma unroll
    for (int m = 0; m < 4; ++m)
        #pragma unroll
        for (int n = 0; n < 4; ++n) acc[m][n] = z4;

    const int KT = IDIM / 64;   // 32
    for (int kt = 0; kt < KT; ++kt) {
        #pragma unroll
        for (int i = 0; i < 4; ++i) {
            gload_lds16(aSrc[i] + kt * 64, &As[ldsOff[i]]);
            gload_lds16(bSrc[i] + kt * 64, &Bs[ldsOff[i]]);
        }
        __syncthreads();
        #pragma unroll
        for (int kk = 0; kk < 2; ++kk) {
            short8 av[4], bv[4];
            int ko = kk * 4 + l16;
            #pragma unroll
            for (int m = 0; m < 4; ++m) {
                int row = wm * 64 + m * 16 + ln15;
                av[m] = *(const short8*)(As + row * 64 + ((ko ^ (row & 7)) * 8));
            }
            #pragma unroll
            for (int n = 0; n < 4; ++n) {
                int row = wn * 64 + n * 16 + ln15;
                bv[n] = *(const short8*)(Bs + row * 64 + ((ko ^ (row & 7)) * 8));
            }
            __builtin_amdgcn_s_setprio(1);
            #pragma unroll
            for (int m = 0; m < 4; ++m)
                #pragma unroll
                for (int n = 0; n < 4; ++n)
                    acc[m][n] = MFMA16(av[m], bv[n], acc[m][n]);
            __builtin_amdgcn_s_setprio(0);
        }
        __syncthreads();
    }

    // fused combine: out[tok] += tokw * acc (2 contributions per element total)
    #pragma unroll
    for (int m = 0; m < 4; ++m) {
        #pragma unroll
        for (int i = 0; i < 4; ++i) {
            int r = mt * 128 + wm * 64 + m * 16 + l16 * 4 + i;
            if (r >= cnt_e) continue;
            int tok = tokid[off_e + r];
            float wgt = tokw[off_e + r];
            float* orow = out + (size_t)tok * HDIM;
            #pragma unroll
            for (int n = 0; n < 4; ++n) {
                int col = nt * 128 + wn * 64 + n * 16 + ln15;
                atomicAdd(&orow[col], wgt * acc[m][n][i]);
            }
        }
    }
}

// ---------------- launch ----------------

extern "C" void kernel_launch(void* const* d_in, const int* in_sizes, int n_in,
                              void* d_out, int out_size, void* d_ws, size_t ws_size,
                              hipStream_t stream) {
    const float* x      = (const float*)d_in[0];
    const float* logits = (const float*)d_in[1];
    const float* w13    = (const float*)d_in[2];
    const float* w2     = (const float*)d_in[3];
    float* out = (float*)d_out;

    char* ws = (char*)d_ws;
    size_t off = 0;
    auto carve = [&](size_t bytes) -> void* {
        void* p = ws + off;
        off = (off + bytes + 255) & ~(size_t)255;
        return p;
    };
    int*   offs   = (int*)carve((NEXP + 1) * 4);
    int*   work   = (int*)carve(128 * 4);
    int*   tokid  = (int*)carve((size_t)(T_TOK * TOPK + 256) * 4);
    float* tokw   = (float*)carve((size_t)T_TOK * TOPK * 4);
    unsigned short* xb   = (unsigned short*)carve((size_t)T_TOK * HDIM * 2);
    unsigned short* w13b = (unsigned short*)carve((size_t)NEXP * 2 * IDIM * HDIM * 2);
    unsigned short* w2b  = (unsigned short*)carve((size_t)NEXP * HDIM * IDIM * 2);
    unsigned short* hbuf = (unsigned short*)carve((size_t)T_TOK * TOPK * IDIM * 2);

    hipMemsetAsync(out, 0, (size_t)T_TOK * HDIM * sizeof(float), stream);
    prep_k<<<1024, 1024, 0, stream>>>(logits, x, w13, offs, work, tokid, tokw, xb, w13b);
    g1c2_k<<<G1B + CVTB, 256, 0, stream>>>(xb, w13b, w2, w2b, tokid, offs, work, hbuf);
    gemm2c_k<<<dim3(8, 72, 1), 256, 0, stream>>>(hbuf, w2b, tokid, offs, work, tokw, out);
}

// Round 15
// 213.956 us; speedup vs baseline: 3.1650x; 3.1650x over previous
//
#include <hip/hip_runtime.h>
#include <hip/hip_bf16.h>
#include <stdint.h>

#define T_TOK 4096
#define NEXP  8
#define HDIM  1024
#define IDIM  2048
#define TOPK  2

typedef __attribute__((ext_vector_type(8))) short short8;
typedef __attribute__((ext_vector_type(4))) float f32x4;

__device__ __forceinline__ unsigned short f2bf(float f) {
    union { float f; unsigned int u; } v; v.f = f;
    unsigned int u = v.u;
    return (unsigned short)((u + 0x7fffu + ((u >> 16) & 1u)) >> 16);
}
__device__ __forceinline__ void gload_lds16(const void* g, void* l) {
    __builtin_amdgcn_global_load_lds(
        (const __attribute__((address_space(1))) unsigned int*)g,
        (__attribute__((address_space(3))) unsigned int*)l,
        16, 0, 0);
}
#define MFMA16(A, B, C) __builtin_amdgcn_mfma_f32_16x16x32_bf16(A, B, C, 0, 0, 0)

// ---------------- prep: routing (block 0) ∥ x+w13 fp32->bf16 (blocks 1+) ----------------

__global__ __launch_bounds__(1024) void prep_k(
    const float* __restrict__ logits, const float* __restrict__ x,
    const float* __restrict__ w13, int* __restrict__ offs, int* __restrict__ work,
    int* __restrict__ tokid, float* __restrict__ tokw,
    unsigned short* __restrict__ xb, unsigned short* __restrict__ w13b)
{
    const int tid = threadIdx.x;
    if (blockIdx.x == 0) {
        __shared__ int cnt[NEXP];
        __shared__ int cur[NEXP];
        if (tid < NEXP) cnt[tid] = 0;
        __syncthreads();
        int e0v[4], e1v[4];
        float w0v[4], w1v[4];
        #pragma unroll
        for (int it = 0; it < 4; ++it) {
            int t = tid + it * 1024;
            const float4* lp = (const float4*)(logits + (size_t)t * NEXP);
            float4 a = lp[0], b = lp[1];
            float l[NEXP] = {a.x, a.y, a.z, a.w, b.x, b.y, b.z, b.w};
            int e0 = 0; float b0 = l[0];
            #pragma unroll
            for (int e = 1; e < NEXP; ++e) if (l[e] > b0) { b0 = l[e]; e0 = e; }
            int e1 = -1; float b1 = -1e30f;
            #pragma unroll
            for (int e = 0; e < NEXP; ++e) { if (e == e0) continue; if (l[e] > b1) { b1 = l[e]; e1 = e; } }
            float tt = __expf(b1 - b0);
            float w0 = 1.0f / (1.0f + tt);
            e0v[it] = e0; e1v[it] = e1; w0v[it] = w0; w1v[it] = 1.0f - w0;
            atomicAdd(&cnt[e0], 1);
            atomicAdd(&cnt[e1], 1);
        }
        __syncthreads();
        if (tid == 0) {
            int s = 0, n = 0;
            for (int e = 0; e < NEXP; ++e) {
                offs[e] = s; cur[e] = s;
                int nm = (cnt[e] + 127) >> 7;
                for (int m = 0; m < nm; ++m) work[1 + n++] = (e << 8) | m;
                s += cnt[e];
            }
            offs[NEXP] = s;
            work[0] = n;
        }
        __syncthreads();
        #pragma unroll
        for (int it = 0; it < 4; ++it) {
            int t = tid + it * 1024;
            int p0 = atomicAdd(&cur[e0v[it]], 1);
            tokid[p0] = t; tokw[p0] = w0v[it];
            int p1 = atomicAdd(&cur[e1v[it]], 1);
            tokid[p1] = t; tokw[p1] = w1v[it];
        }
        return;
    }
    const int n0 = T_TOK * HDIM / 8;
    const int n1 = NEXP * 2 * IDIM * HDIM / 8;
    const int total = n0 + n1;
    for (int i = (blockIdx.x - 1) * 1024 + tid; i < total; i += (int)(gridDim.x - 1) * 1024) {
        const float* s; unsigned short* d; int j;
        if (i < n0) { s = x; d = xb; j = i; }
        else { s = w13; d = w13b; j = i - n0; }
        const float4* p4 = (const float4*)(s + (size_t)j * 8);
        float4 a = p4[0], b = p4[1];
        union { unsigned short us[8]; short8 v; } r;
        r.us[0] = f2bf(a.x); r.us[1] = f2bf(a.y); r.us[2] = f2bf(a.z); r.us[3] = f2bf(a.w);
        r.us[4] = f2bf(b.x); r.us[5] = f2bf(b.y); r.us[6] = f2bf(b.z); r.us[7] = f2bf(b.w);
        *(short8*)(d + (size_t)j * 8) = r.v;
    }
}

// ---------------- g1c2: gemm1 (blocks [0,1152)) ∥ w2 conversion (blocks [1152,1408)) ----------
// gemm1 first in dispatch order; w2-cvt fills retirement raggedness at the tail.
// launch_bounds(256,2): (256,3) forces VGPR cap below live-range need -> scratch
// spill disaster (R14: 1 GB scratch writes, 5x slowdown). Keep 2.

#define G1B  1152   // 16 nt x 72 work slots
#define CVTB 256

__global__ __launch_bounds__(256, 2) void g1c2_k(
    const unsigned short* __restrict__ xb, const unsigned short* __restrict__ w13b,
    const float* __restrict__ w2, unsigned short* __restrict__ w2b,
    const int* __restrict__ tokid, const int* __restrict__ offs,
    const int* __restrict__ work, unsigned short* __restrict__ hbuf)
{
    __shared__ __align__(16) unsigned short As[128 * 64];
    __shared__ __align__(16) unsigned short Bg[128 * 64];
    __shared__ __align__(16) unsigned short Bu[128 * 64];

    const int bid = blockIdx.x;
    if (bid >= G1B) {
        // ---- w2 conversion (tail blocks)
        const int cb = bid - G1B;
        const int n2 = NEXP * HDIM * IDIM / 8;
        for (int i = cb * 256 + threadIdx.x; i < n2; i += CVTB * 256) {
            const float4* p4 = (const float4*)(w2 + (size_t)i * 8);
            float4 a = p4[0], b = p4[1];
            union { unsigned short us[8]; short8 v; } r;
            r.us[0] = f2bf(a.x); r.us[1] = f2bf(a.y); r.us[2] = f2bf(a.z); r.us[3] = f2bf(a.w);
            r.us[4] = f2bf(b.x); r.us[5] = f2bf(b.y); r.us[6] = f2bf(b.z); r.us[7] = f2bf(b.w);
            *(short8*)(w2b + (size_t)i * 8) = r.v;
        }
        return;
    }

    const int id = bid;                              // 0..1151
    const int id2 = (id & 7) * 144 + (id >> 3);      // XCD-chunked bijective swizzle
    const int nt = id2 / 72;
    const int wki = id2 % 72;
    if (wki >= work[0]) return;
    const int wk = work[1 + wki];
    const int e = wk >> 8, mt = wk & 255;
    const int off_e = offs[e];
    const int cnt_e = offs[e + 1] - off_e;

    const int tid = threadIdx.x;
    const int w = tid >> 6, lane = tid & 63;
    const int ln15 = lane & 15, l16 = lane >> 4;
    const int wm = w >> 1, wn = w & 1;

    const unsigned short* aSrc[4]; const unsigned short* gSrc[4]; const unsigned short* uSrc[4];
    int ldsOff[4];
    #pragma unroll
    for (int i = 0; i < 4; ++i) {
        int S = (i * 4 + w) * 64 + lane;
        int row = S >> 3;
        int ko = (S & 7) ^ (row & 7);
        ldsOff[i] = (i * 4 + w) * 512;
        int tr = mt * 128 + row; if (tr >= cnt_e) tr = cnt_e - 1;
        aSrc[i] = xb + (size_t)tokid[off_e + tr] * HDIM + ko * 8;
        gSrc[i] = w13b + (size_t)e * (2 * IDIM * HDIM) + (size_t)(nt * 128 + row) * HDIM + ko * 8;
        uSrc[i] = w13b + (size_t)e * (2 * IDIM * HDIM) + (size_t)(IDIM + nt * 128 + row) * HDIM + ko * 8;
    }

    const f32x4 z4 = {0.f, 0.f, 0.f, 0.f};
    f32x4 g[4][4], u[4][4];
    #pragma unroll
    for (int m = 0; m < 4; ++m)
        #pragma unroll
        for (int n = 0; n < 4; ++n) { g[m][n] = z4; u[m][n] = z4; }

    const int KT = HDIM / 64;   // 16
    for (int kt = 0; kt < KT; ++kt) {
        #pragma unroll
        for (int i = 0; i < 4; ++i) {
            gload_lds16(aSrc[i] + kt * 64, &As[ldsOff[i]]);
            gload_lds16(gSrc[i] + kt * 64, &Bg[ldsOff[i]]);
            gload_lds16(uSrc[i] + kt * 64, &Bu[ldsOff[i]]);
        }
        __syncthreads();
        #pragma unroll
        for (int kk = 0; kk < 2; ++kk) {
            short8 av[4], bgv[4], buv[4];
            int ko = kk * 4 + l16;
            #pragma unroll
            for (int m = 0; m < 4; ++m) {
                int row = wm * 64 + m * 16 + ln15;
                av[m] = *(const short8*)(As + row * 64 + ((ko ^ (row & 7)) * 8));
            }
            #pragma unroll
            for (int n = 0; n < 4; ++n) {
                int row = wn * 64 + n * 16 + ln15;
                int idx = row * 64 + ((ko ^ (row & 7)) * 8);
                bgv[n] = *(const short8*)(Bg + idx);
                buv[n] = *(const short8*)(Bu + idx);
            }
            __builtin_amdgcn_s_setprio(1);
            #pragma unroll
            for (int m = 0; m < 4; ++m)
                #pragma unroll
                for (int n = 0; n < 4; ++n) {
                    g[m][n] = MFMA16(av[m], bgv[n], g[m][n]);
                    u[m][n] = MFMA16(av[m], buv[n], u[m][n]);
                }
            __builtin_amdgcn_s_setprio(0);
        }
        __syncthreads();
    }

    // epilogue: h = silu(gate) * up -> bf16
    #pragma unroll
    for (int m = 0; m < 4; ++m) {
        #pragma unroll
        for (int i = 0; i < 4; ++i) {
            int r = mt * 128 + wm * 64 + m * 16 + l16 * 4 + i;
            if (r >= cnt_e) continue;
            size_t rb = (size_t)(off_e + r) * IDIM;
            #pragma unroll
            for (int n = 0; n < 4; ++n) {
                int col = nt * 128 + wn * 64 + n * 16 + ln15;
                float gv = g[m][n][i], uv = u[m][n][i];
                float hv = gv / (1.f + __expf(-gv)) * uv;
                hbuf[rb + col] = f2bf(hv);
            }
        }
    }
}

// ---------------- gemm2c: (h @ W2^T) * tokw + fused combine via f32 atomicAdd ----------------

__global__ __launch_bounds__(256, 2) void gemm2c_k(
    const unsigned short* __restrict__ hbuf, const unsigned short* __restrict__ w2b,
    const int* __restrict__ tokid, const int* __restrict__ offs,
    const int* __restrict__ work, const float* __restrict__ tokw,
    float* __restrict__ out)
{
    __shared__ __align__(16) unsigned short As[128 * 64];
    __shared__ __align__(16) unsigned short Bs[128 * 64];

    const int id = blockIdx.y * gridDim.x + blockIdx.x;   // 0..575
    const int id2 = (id & 7) * 72 + (id >> 3);
    const int nt = id2 / 72;
    const int wki = id2 % 72;
    if (wki >= work[0]) return;
    const int wk = work[1 + wki];
    const int e = wk >> 8, mt = wk & 255;
    const int off_e = offs[e];
    const int cnt_e = offs[e + 1] - off_e;

    const int tid = threadIdx.x;
    const int w = tid >> 6, lane = tid & 63;
    const int ln15 = lane & 15, l16 = lane >> 4;
    const int wm = w >> 1, wn = w & 1;

    const unsigned short* aSrc[4]; const unsigned short* bSrc[4];
    int ldsOff[4];
    #pragma unroll
    for (int i = 0; i < 4; ++i) {
        int S = (i * 4 + w) * 64 + lane;
        int row = S >> 3;
        int ko = (S & 7) ^ (row & 7);
        ldsOff[i] = (i * 4 + w) * 512;
        int tr = mt * 128 + row; if (tr >= cnt_e) tr = cnt_e - 1;
        aSrc[i] = hbuf + (size_t)(off_e + tr) * IDIM + ko * 8;
        bSrc[i] = w2b + (size_t)e * (HDIM * IDIM) + (size_t)(nt * 128 + row) * IDIM + ko * 8;
    }

    const f32x4 z4 = {0.f, 0.f, 0.f, 0.f};
    f32x4 acc[4][4];
    #pragma unroll
    for (int m = 0; m < 4; ++m)
        #pragma unroll
        for (int n = 0; n < 4; ++n) acc[m][n] = z4;

    const int KT = IDIM / 64;   // 32
    for (int kt = 0; kt < KT; ++kt) {
        #pragma unroll
        for (int i = 0; i < 4; ++i) {
            gload_lds16(aSrc[i] + kt * 64, &As[ldsOff[i]]);
            gload_lds16(bSrc[i] + kt * 64, &Bs[ldsOff[i]]);
        }
        __syncthreads();
        #pragma unroll
        for (int kk = 0; kk < 2; ++kk) {
            short8 av[4], bv[4];
            int ko = kk * 4 + l16;
            #pragma unroll
            for (int m = 0; m < 4; ++m) {
                int row = wm * 64 + m * 16 + ln15;
                av[m] = *(const short8*)(As + row * 64 + ((ko ^ (row & 7)) * 8));
            }
            #pragma unroll
            for (int n = 0; n < 4; ++n) {
                int row = wn * 64 + n * 16 + ln15;
                bv[n] = *(const short8*)(Bs + row * 64 + ((ko ^ (row & 7)) * 8));
            }
            __builtin_amdgcn_s_setprio(1);
            #pragma unroll
            for (int m = 0; m < 4; ++m)
                #pragma unroll
                for (int n = 0; n < 4; ++n)
                    acc[m][n] = MFMA16(av[m], bv[n], acc[m][n]);
            __builtin_amdgcn_s_setprio(0);
        }
        __syncthreads();
    }

    // fused combine: out[tok] += tokw * acc (2 contributions per element total)
    #pragma unroll
    for (int m = 0; m < 4; ++m) {
        #pragma unroll
        for (int i = 0; i < 4; ++i) {
            int r = mt * 128 + wm * 64 + m * 16 + l16 * 4 + i;
            if (r >= cnt_e) continue;
            int tok = tokid[off_e + r];
            float wgt = tokw[off_e + r];
            float* orow = out + (size_t)tok * HDIM;
            #pragma unroll
            for (int n = 0; n < 4; ++n) {
                int col = nt * 128 + wn * 64 + n * 16 + ln15;
                atomicAdd(&orow[col], wgt * acc[m][n][i]);
            }
        }
    }
}

// ---------------- launch ----------------

extern "C" void kernel_launch(void* const* d_in, const int* in_sizes, int n_in,
                              void* d_out, int out_size, void* d_ws, size_t ws_size,
                              hipStream_t stream) {
    const float* x      = (const float*)d_in[0];
    const float* logits = (const float*)d_in[1];
    const float* w13    = (const float*)d_in[2];
    const float* w2     = (const float*)d_in[3];
    float* out = (float*)d_out;

    char* ws = (char*)d_ws;
    size_t off = 0;
    auto carve = [&](size_t bytes) -> void* {
        void* p = ws + off;
        off = (off + bytes + 255) & ~(size_t)255;
        return p;
    };
    int*   offs   = (int*)carve((NEXP + 1) * 4);
    int*   work   = (int*)carve(128 * 4);
    int*   tokid  = (int*)carve((size_t)(T_TOK * TOPK + 256) * 4);
    float* tokw   = (float*)carve((size_t)T_TOK * TOPK * 4);
    unsigned short* xb   = (unsigned short*)carve((size_t)T_TOK * HDIM * 2);
    unsigned short* w13b = (unsigned short*)carve((size_t)NEXP * 2 * IDIM * HDIM * 2);
    unsigned short* w2b  = (unsigned short*)carve((size_t)NEXP * HDIM * IDIM * 2);
    unsigned short* hbuf = (unsigned short*)carve((size_t)T_TOK * TOPK * IDIM * 2);

    hipMemsetAsync(out, 0, (size_t)T_TOK * HDIM * sizeof(float), stream);
    prep_k<<<1024, 1024, 0, stream>>>(logits, x, w13, offs, work, tokid, tokw, xb, w13b);
    g1c2_k<<<G1B + CVTB, 256, 0, stream>>>(xb, w13b, w2, w2b, tokid, offs, work, hbuf);
    gemm2c_k<<<dim3(8, 72, 1), 256, 0, stream>>>(hbuf, w2b, tokid, offs, work, tokw, out);
}

// Round 16
// 208.347 us; speedup vs baseline: 3.2502x; 1.0269x over previous
//
#include <hip/hip_runtime.h>
#include <hip/hip_bf16.h>
#include <stdint.h>

#define T_TOK 4096
#define NEXP  8
#define HDIM  1024
#define IDIM  2048
#define TOPK  2

typedef __attribute__((ext_vector_type(8))) short short8;
typedef __attribute__((ext_vector_type(4))) float f32x4;

__device__ __forceinline__ unsigned short f2bf(float f) {
    union { float f; unsigned int u; } v; v.f = f;
    unsigned int u = v.u;
    return (unsigned short)((u + 0x7fffu + ((u >> 16) & 1u)) >> 16);
}
__device__ __forceinline__ void gload_lds16(const void* g, void* l) {
    __builtin_amdgcn_global_load_lds(
        (const __attribute__((address_space(1))) unsigned int*)g,
        (__attribute__((address_space(3))) unsigned int*)l,
        16, 0, 0);
}
#define MFMA16(A, B, C) __builtin_amdgcn_mfma_f32_16x16x32_bf16(A, B, C, 0, 0, 0)

// ---------------- prep: routing (block 0) ∥ out-zeroing + x+w13 fp32->bf16 (blocks 1+) --------

__global__ __launch_bounds__(1024) void prep_k(
    const float* __restrict__ logits, const float* __restrict__ x,
    const float* __restrict__ w13, int* __restrict__ offs, int* __restrict__ work,
    int* __restrict__ tokid, float* __restrict__ tokw,
    unsigned short* __restrict__ xb, unsigned short* __restrict__ w13b,
    float* __restrict__ out)
{
    const int tid = threadIdx.x;
    if (blockIdx.x == 0) {
        __shared__ int cnt[NEXP];
        __shared__ int cur[NEXP];
        if (tid < NEXP) cnt[tid] = 0;
        __syncthreads();
        int e0v[4], e1v[4];
        float w0v[4], w1v[4];
        #pragma unroll
        for (int it = 0; it < 4; ++it) {
            int t = tid + it * 1024;
            const float4* lp = (const float4*)(logits + (size_t)t * NEXP);
            float4 a = lp[0], b = lp[1];
            float l[NEXP] = {a.x, a.y, a.z, a.w, b.x, b.y, b.z, b.w};
            int e0 = 0; float b0 = l[0];
            #pragma unroll
            for (int e = 1; e < NEXP; ++e) if (l[e] > b0) { b0 = l[e]; e0 = e; }
            int e1 = -1; float b1 = -1e30f;
            #pragma unroll
            for (int e = 0; e < NEXP; ++e) { if (e == e0) continue; if (l[e] > b1) { b1 = l[e]; e1 = e; } }
            float tt = __expf(b1 - b0);
            float w0 = 1.0f / (1.0f + tt);
            e0v[it] = e0; e1v[it] = e1; w0v[it] = w0; w1v[it] = 1.0f - w0;
            atomicAdd(&cnt[e0], 1);
            atomicAdd(&cnt[e1], 1);
        }
        __syncthreads();
        if (tid == 0) {
            int s = 0, n = 0;
            for (int e = 0; e < NEXP; ++e) {
                offs[e] = s; cur[e] = s;
                int nm = (cnt[e] + 127) >> 7;
                for (int m = 0; m < nm; ++m) work[1 + n++] = (e << 8) | m;
                s += cnt[e];
            }
            offs[NEXP] = s;
            work[0] = n;
        }
        __syncthreads();
        #pragma unroll
        for (int it = 0; it < 4; ++it) {
            int t = tid + it * 1024;
            int p0 = atomicAdd(&cur[e0v[it]], 1);
            tokid[p0] = t; tokw[p0] = w0v[it];
            int p1 = atomicAdd(&cur[e1v[it]], 1);
            tokid[p1] = t; tokw[p1] = w1v[it];
        }
        return;
    }
    // blocks 1+: zero out (consumed by gemm2c two kernels later) + convert x, w13
    const int nz = T_TOK * HDIM / 4;                 // float4 zero-stores
    const int n0 = T_TOK * HDIM / 8;
    const int n1 = NEXP * 2 * IDIM * HDIM / 8;
    const int total = nz + n0 + n1;
    const float4 zero4 = {0.f, 0.f, 0.f, 0.f};
    for (int i = (blockIdx.x - 1) * 1024 + tid; i < total; i += (int)(gridDim.x - 1) * 1024) {
        if (i < nz) { ((float4*)out)[i] = zero4; continue; }
        int ii = i - nz;
        const float* s; unsigned short* d; int j;
        if (ii < n0) { s = x; d = xb; j = ii; }
        else { s = w13; d = w13b; j = ii - n0; }
        const float4* p4 = (const float4*)(s + (size_t)j * 8);
        float4 a = p4[0], b = p4[1];
        union { unsigned short us[8]; short8 v; } r;
        r.us[0] = f2bf(a.x); r.us[1] = f2bf(a.y); r.us[2] = f2bf(a.z); r.us[3] = f2bf(a.w);
        r.us[4] = f2bf(b.x); r.us[5] = f2bf(b.y); r.us[6] = f2bf(b.z); r.us[7] = f2bf(b.w);
        *(short8*)(d + (size_t)j * 8) = r.v;
    }
}

// ---------------- g1c2: gemm1 (blocks [0,1152)) ∥ w2 conversion (blocks [1152,1408)) ----------
// gemm1 first in dispatch order; w2-cvt fills retirement raggedness at the tail.
// launch_bounds(256,2): (256,3) caps VGPR below live-range need -> scratch spill
// disaster (R14: 1 GB scratch writes, 5x slowdown). Keep 2.

#define G1B  1152   // 16 nt x 72 work slots
#define CVTB 256

__global__ __launch_bounds__(256, 2) void g1c2_k(
    const unsigned short* __restrict__ xb, const unsigned short* __restrict__ w13b,
    const float* __restrict__ w2, unsigned short* __restrict__ w2b,
    const int* __restrict__ tokid, const int* __restrict__ offs,
    const int* __restrict__ work, unsigned short* __restrict__ hbuf)
{
    __shared__ __align__(16) unsigned short As[128 * 64];
    __shared__ __align__(16) unsigned short Bg[128 * 64];
    __shared__ __align__(16) unsigned short Bu[128 * 64];

    const int bid = blockIdx.x;
    if (bid >= G1B) {
        const int cb = bid - G1B;
        const int n2 = NEXP * HDIM * IDIM / 8;
        for (int i = cb * 256 + threadIdx.x; i < n2; i += CVTB * 256) {
            const float4* p4 = (const float4*)(w2 + (size_t)i * 8);
            float4 a = p4[0], b = p4[1];
            union { unsigned short us[8]; short8 v; } r;
            r.us[0] = f2bf(a.x); r.us[1] = f2bf(a.y); r.us[2] = f2bf(a.z); r.us[3] = f2bf(a.w);
            r.us[4] = f2bf(b.x); r.us[5] = f2bf(b.y); r.us[6] = f2bf(b.z); r.us[7] = f2bf(b.w);
            *(short8*)(w2b + (size_t)i * 8) = r.v;
        }
        return;
    }

    const int id = bid;                              // 0..1151
    const int id2 = (id & 7) * 144 + (id >> 3);      // XCD-chunked bijective swizzle
    const int nt = id2 / 72;
    const int wki = id2 % 72;
    if (wki >= work[0]) return;
    const int wk = work[1 + wki];
    const int e = wk >> 8, mt = wk & 255;
    const int off_e = offs[e];
    const int cnt_e = offs[e + 1] - off_e;

    const int tid = threadIdx.x;
    const int w = tid >> 6, lane = tid & 63;
    const int ln15 = lane & 15, l16 = lane >> 4;
    const int wm = w >> 1, wn = w & 1;

    const unsigned short* aSrc[4]; const unsigned short* gSrc[4]; const unsigned short* uSrc[4];
    int ldsOff[4];
    #pragma unroll
    for (int i = 0; i < 4; ++i) {
        int S = (i * 4 + w) * 64 + lane;
        int row = S >> 3;
        int ko = (S & 7) ^ (row & 7);
        ldsOff[i] = (i * 4 + w) * 512;
        int tr = mt * 128 + row; if (tr >= cnt_e) tr = cnt_e - 1;
        aSrc[i] = xb + (size_t)tokid[off_e + tr] * HDIM + ko * 8;
        gSrc[i] = w13b + (size_t)e * (2 * IDIM * HDIM) + (size_t)(nt * 128 + row) * HDIM + ko * 8;
        uSrc[i] = w13b + (size_t)e * (2 * IDIM * HDIM) + (size_t)(IDIM + nt * 128 + row) * HDIM + ko * 8;
    }

    const f32x4 z4 = {0.f, 0.f, 0.f, 0.f};
    f32x4 g[4][4], u[4][4];
    #pragma unroll
    for (int m = 0; m < 4; ++m)
        #pragma unroll
        for (int n = 0; n < 4; ++n) { g[m][n] = z4; u[m][n] = z4; }

    const int KT = HDIM / 64;   // 16
    for (int kt = 0; kt < KT; ++kt) {
        #pragma unroll
        for (int i = 0; i < 4; ++i) {
            gload_lds16(aSrc[i] + kt * 64, &As[ldsOff[i]]);
            gload_lds16(gSrc[i] + kt * 64, &Bg[ldsOff[i]]);
            gload_lds16(uSrc[i] + kt * 64, &Bu[ldsOff[i]]);
        }
        __syncthreads();
        #pragma unroll
        for (int kk = 0; kk < 2; ++kk) {
            short8 av[4], bgv[4], buv[4];
            int ko = kk * 4 + l16;
            #pragma unroll
            for (int m = 0; m < 4; ++m) {
                int row = wm * 64 + m * 16 + ln15;
                av[m] = *(const short8*)(As + row * 64 + ((ko ^ (row & 7)) * 8));
            }
            #pragma unroll
            for (int n = 0; n < 4; ++n) {
                int row = wn * 64 + n * 16 + ln15;
                int idx = row * 64 + ((ko ^ (row & 7)) * 8);
                bgv[n] = *(const short8*)(Bg + idx);
                buv[n] = *(const short8*)(Bu + idx);
            }
            __builtin_amdgcn_s_setprio(1);
            #pragma unroll
            for (int m = 0; m < 4; ++m)
                #pragma unroll
                for (int n = 0; n < 4; ++n) {
                    g[m][n] = MFMA16(av[m], bgv[n], g[m][n]);
                    u[m][n] = MFMA16(av[m], buv[n], u[m][n]);
                }
            __builtin_amdgcn_s_setprio(0);
        }
        __syncthreads();
    }

    // epilogue: h = silu(gate) * up -> bf16
    #pragma unroll
    for (int m = 0; m < 4; ++m) {
        #pragma unroll
        for (int i = 0; i < 4; ++i) {
            int r = mt * 128 + wm * 64 + m * 16 + l16 * 4 + i;
            if (r >= cnt_e) continue;
            size_t rb = (size_t)(off_e + r) * IDIM;
            #pragma unroll
            for (int n = 0; n < 4; ++n) {
                int col = nt * 128 + wn * 64 + n * 16 + ln15;
                float gv = g[m][n][i], uv = u[m][n][i];
                float hv = gv / (1.f + __expf(-gv)) * uv;
                hbuf[rb + col] = f2bf(hv);
            }
        }
    }
}

// ---------------- gemm2c: (h @ W2^T) * tokw + fused combine via f32 atomicAdd ----------------

__global__ __launch_bounds__(256, 2) void gemm2c_k(
    const unsigned short* __restrict__ hbuf, const unsigned short* __restrict__ w2b,
    const int* __restrict__ tokid, const int* __restrict__ offs,
    const int* __restrict__ work, const float* __restrict__ tokw,
    float* __restrict__ out)
{
    __shared__ __align__(16) unsigned short As[128 * 64];
    __shared__ __align__(16) unsigned short Bs[128 * 64];

    const int id = blockIdx.y * gridDim.x + blockIdx.x;   // 0..575
    const int id2 = (id & 7) * 72 + (id >> 3);
    const int nt = id2 / 72;
    const int wki = id2 % 72;
    if (wki >= work[0]) return;
    const int wk = work[1 + wki];
    const int e = wk >> 8, mt = wk & 255;
    const int off_e = offs[e];
    const int cnt_e = offs[e + 1] - off_e;

    const int tid = threadIdx.x;
    const int w = tid >> 6, lane = tid & 63;
    const int ln15 = lane & 15, l16 = lane >> 4;
    const int wm = w >> 1, wn = w & 1;

    const unsigned short* aSrc[4]; const unsigned short* bSrc[4];
    int ldsOff[4];
    #pragma unroll
    for (int i = 0; i < 4; ++i) {
        int S = (i * 4 + w) * 64 + lane;
        int row = S >> 3;
        int ko = (S & 7) ^ (row & 7);
        ldsOff[i] = (i * 4 + w) * 512;
        int tr = mt * 128 + row; if (tr >= cnt_e) tr = cnt_e - 1;
        aSrc[i] = hbuf + (size_t)(off_e + tr) * IDIM + ko * 8;
        bSrc[i] = w2b + (size_t)e * (HDIM * IDIM) + (size_t)(nt * 128 + row) * IDIM + ko * 8;
    }

    const f32x4 z4 = {0.f, 0.f, 0.f, 0.f};
    f32x4 acc[4][4];
    #pragma unroll
    for (int m = 0; m < 4; ++m)
        #pragma unroll
        for (int n = 0; n < 4; ++n) acc[m][n] = z4;

    const int KT = IDIM / 64;   // 32
    for (int kt = 0; kt < KT; ++kt) {
        #pragma unroll
        for (int i = 0; i < 4; ++i) {
            gload_lds16(aSrc[i] + kt * 64, &As[ldsOff[i]]);
            gload_lds16(bSrc[i] + kt * 64, &Bs[ldsOff[i]]);
        }
        __syncthreads();
        #pragma unroll
        for (int kk = 0; kk < 2; ++kk) {
            short8 av[4], bv[4];
            int ko = kk * 4 + l16;
            #pragma unroll
            for (int m = 0; m < 4; ++m) {
                int row = wm * 64 + m * 16 + ln15;
                av[m] = *(const short8*)(As + row * 64 + ((ko ^ (row & 7)) * 8));
            }
            #pragma unroll
            for (int n = 0; n < 4; ++n) {
                int row = wn * 64 + n * 16 + ln15;
                bv[n] = *(const short8*)(Bs + row * 64 + ((ko ^ (row & 7)) * 8));
            }
            __builtin_amdgcn_s_setprio(1);
            #pragma unroll
            for (int m = 0; m < 4; ++m)
                #pragma unroll
                for (int n = 0; n < 4; ++n)
                    acc[m][n] = MFMA16(av[m], bv[n], acc[m][n]);
            __builtin_amdgcn_s_setprio(0);
        }
        __syncthreads();
    }

    // fused combine: out[tok] += tokw * acc (2 contributions per element total)
    #pragma unroll
    for (int m = 0; m < 4; ++m) {
        #pragma unroll
        for (int i = 0; i < 4; ++i) {
            int r = mt * 128 + wm * 64 + m * 16 + l16 * 4 + i;
            if (r >= cnt_e) continue;
            int tok = tokid[off_e + r];
            float wgt = tokw[off_e + r];
            float* orow = out + (size_t)tok * HDIM;
            #pragma unroll
            for (int n = 0; n < 4; ++n) {
                int col = nt * 128 + wn * 64 + n * 16 + ln15;
                atomicAdd(&orow[col], wgt * acc[m][n][i]);
            }
        }
    }
}

// ---------------- launch ----------------

extern "C" void kernel_launch(void* const* d_in, const int* in_sizes, int n_in,
                              void* d_out, int out_size, void* d_ws, size_t ws_size,
                              hipStream_t stream) {
    const float* x      = (const float*)d_in[0];
    const float* logits = (const float*)d_in[1];
    const float* w13    = (const float*)d_in[2];
    const float* w2     = (const float*)d_in[3];
    float* out = (float*)d_out;

    char* ws = (char*)d_ws;
    size_t off = 0;
    auto carve = [&](size_t bytes) -> void* {
        void* p = ws + off;
        off = (off + bytes + 255) & ~(size_t)255;
        return p;
    };
    int*   offs   = (int*)carve((NEXP + 1) * 4);
    int*   work   = (int*)carve(128 * 4);
    int*   tokid  = (int*)carve((size_t)(T_TOK * TOPK + 256) * 4);
    float* tokw   = (float*)carve((size_t)T_TOK * TOPK * 4);
    unsigned short* xb   = (unsigned short*)carve((size_t)T_TOK * HDIM * 2);
    unsigned short* w13b = (unsigned short*)carve((size_t)NEXP * 2 * IDIM * HDIM * 2);
    unsigned short* w2b  = (unsigned short*)carve((size_t)NEXP * HDIM * IDIM * 2);
    unsigned short* hbuf = (unsigned short*)carve((size_t)T_TOK * TOPK * IDIM * 2);

    prep_k<<<1024, 1024, 0, stream>>>(logits, x, w13, offs, work, tokid, tokw, xb, w13b, out);
    g1c2_k<<<G1B + CVTB, 256, 0, stream>>>(xb, w13b, w2, w2b, tokid, offs, work, hbuf);
    gemm2c_k<<<dim3(8, 72, 1), 256, 0, stream>>>(hbuf, w2b, tokid, offs, work, tokw, out);
}